// Round 6
// baseline (188.409 us; speedup 1.0000x reference)
//
#include <hip/hip_runtime.h>

constexpr int Lc = 16;
constexpr int Cc = 16;
constexpr int Hc = 128;
constexpr int Wc = 256;
constexpr float DECAYc = 0.1f;
constexpr int HWc = Hc * Wc;

// ---------------------------------------------------------------------------
// Kernel 1: transpose img (L,C,H,W) -> imgT (L,H,W,C), direct (no LDS).
// Block = 256 thr = (wq 0..63, q 0..3); each iter r: thread reads 4 floats
// from planes 4q..4q+3 at px (coalesced 256B runs per plane) and writes one
// float4 at px*64B + q*16B (4 KB fully contiguous per instr).
// ---------------------------------------------------------------------------
__global__ __launch_bounds__(256) void transpose_chlast(
    const float* __restrict__ img, float* __restrict__ imgT)
{
    const int tid = threadIdx.x;
    const int q  = tid & 3;
    const int wq = tid >> 2;
    const int kf  = blockIdx.x >> 6;     // frame 0..15
    const int seg = blockIdx.x & 63;     // 64 segments/frame
    const int px0 = seg * 512;
    const float* __restrict__ srcb = img + (size_t)kf * Cc * HWc;
#pragma unroll
    for (int r = 0; r < 8; ++r) {
        const int px = px0 + r * 64 + wq;
        float4 v;
        v.x = srcb[(4 * q + 0) * HWc + px];
        v.y = srcb[(4 * q + 1) * HWc + px];
        v.z = srcb[(4 * q + 2) * HWc + px];
        v.w = srcb[(4 * q + 3) * HWc + px];
        ((float4*)(imgT + ((size_t)kf * HWc + px) * Cc))[q] = v;
    }
}

// ---------------------------------------------------------------------------
// Kernel 2: t-quarter-split warp-accumulate.
// Block b = [sub(6) | r(2) | band(3)]: band = b&7 (XCD-aligned 16-row band),
// r = (b>>3)&3 (t residue: t = 4i+r), sub = b>>5 (pixel group).
// 2048 blocks -> 8 blocks/CU; acc[4] float4 keeps VGPRs low for occupancy.
// Lane = 4*wq + q: 4 lanes cover one pixel's 64B channels-last line ->
// every gather instr coalesces to 16 full-line requests (minimum).
// k==t is an exact identity sample (coords bit-exact, weight 1): direct add.
// ---------------------------------------------------------------------------
__global__ __launch_bounds__(256, 6) void gridsample_tquarter(
    const float* __restrict__ imgT,      // (L, H, W, C)
    const float* __restrict__ cum_flow,  // (L, 2, H, W)
    const float* __restrict__ mask,      // (L, L)
    const float* __restrict__ decay,     // (L, L)
    float* __restrict__ out)             // (L, C, H, W)
{
    __shared__ float wtab[Lc * Lc];
    const int tid = threadIdx.x;
    if (tid < Lc * Lc)
        wtab[tid] = mask[tid] * __expf(-DECAYc * decay[tid]);
    __syncthreads();

    const int q  = tid & 3;              // channel quarter
    const int wq = tid >> 2;             // pixel-in-group 0..63
    const int b = blockIdx.x;            // 0..2047
    const int band = b & 7;              // 16-row band (XCD heuristic)
    const int r    = (b >> 3) & 3;       // t residue
    const int sub  = b >> 5;             // 0..63
    const int h = band * 16 + (sub >> 2);
    const int w = (sub & 3) * 64 + wq;
    const int pix = h * Wc + w;

    const float base_x = w * (2.0f / Wc) - 1.0f + 1.0f / Wc;
    const float base_y = h * (2.0f / Hc) - 1.0f + 1.0f / Hc;

    // Pre-added per-t terms: mod-arg = sx1[i] - fxk ; gy+1 = sy1[i] - fyk
    float sx1[4], sy1[4];
#pragma unroll
    for (int i = 0; i < 4; ++i) {
        const int t = 4 * i + r;
        sx1[i] = base_x + cum_flow[(t * 2 + 0) * HWc + pix] + 1.0f;
        sy1[i] = base_y + cum_flow[(t * 2 + 1) * HWc + pix] + 1.0f;
    }

    float4 acc[4];
#pragma unroll
    for (int i = 0; i < 4; ++i) acc[i] = make_float4(0.f, 0.f, 0.f, 0.f);

    const int kmax = 12 + r;             // largest t this block handles
    for (int k = 0; k <= kmax; ++k) {    // dynamic, wave-uniform
        const float fxk = cum_flow[(k * 2 + 0) * HWc + pix];
        const float fyk = cum_flow[(k * 2 + 1) * HWc + pix];
        const float* __restrict__ bk = imgT + (size_t)k * HWc * Cc;

#pragma unroll
        for (int i = 0; i < 4; ++i) {
            const int t = 4 * i + r;
            if (t < k) continue;         // wave-uniform (k in SGPR)
            if (t == k) {                // identity sample, weight 1
                const float4 idv = ((const float4*)(bk + pix * Cc))[q];
                acc[i].x += idv.x; acc[i].y += idv.y;
                acc[i].z += idv.z; acc[i].w += idv.w;
                continue;
            }
            const float wkt = wtab[t * Lc + k];

            // m = mod(gx+1, 2);  ix = m*W/2 - 0.5
            float m = sx1[i] - fxk;
            m -= 2.0f * floorf(m * 0.5f);
            const float ix = m * (Wc * 0.5f) - 0.5f;
            const float iy = (sy1[i] - fyk) * (Hc * 0.5f) - 0.5f;

            const float x0f = floorf(ix);
            const float y0f = floorf(iy);
            const float wx = ix - x0f;
            const float wy = iy - y0f;

            const int x0 = (int)x0f;
            const int y0 = (int)y0f;
            const int x0r = x0 & (Wc - 1);
            const int x1r = (x0 + 1) & (Wc - 1);
            const int y0c = min(max(y0, 0), Hc - 1);
            const int y1c = min(max(y0 + 1, 0), Hc - 1);

            const float wb = wkt * wy;
            const float wa = wkt - wb;
            const float omx = 1.0f - wx;
            const float a00 = wa * omx;
            const float a10 = wa * wx;
            const float a01 = wb * omx;
            const float a11 = wb * wx;

            const float4 v00 = ((const float4*)(bk + (y0c * Wc + x0r) * Cc))[q];
            const float4 v10 = ((const float4*)(bk + (y0c * Wc + x1r) * Cc))[q];
            const float4 v01 = ((const float4*)(bk + (y1c * Wc + x0r) * Cc))[q];
            const float4 v11 = ((const float4*)(bk + (y1c * Wc + x1r) * Cc))[q];

            acc[i].x += a00 * v00.x + a10 * v10.x + a01 * v01.x + a11 * v11.x;
            acc[i].y += a00 * v00.y + a10 * v10.y + a01 * v01.y + a11 * v11.y;
            acc[i].z += a00 * v00.z + a10 * v10.z + a01 * v01.z + a11 * v11.z;
            acc[i].w += a00 * v00.w + a10 * v10.w + a01 * v01.w + a11 * v11.w;
        }
    }

    // Epilogue: out (L,C,H,W), planes 4q..4q+3 of each handled t.
#pragma unroll
    for (int i = 0; i < 4; ++i) {
        const int t = 4 * i + r;
        float* __restrict__ op = out + ((size_t)t * Cc + 4 * q) * HWc + pix;
        op[0 * HWc] = acc[i].x;
        op[1 * HWc] = acc[i].y;
        op[2 * HWc] = acc[i].z;
        op[3 * HWc] = acc[i].w;
    }
}

// ---------------------------------------------------------------------------
// Fallback (Round-1 kernel): used only if ws_size is too small for imgT.
// ---------------------------------------------------------------------------
__global__ __launch_bounds__(256) void gridsample_warp_acc(
    const float* __restrict__ img, const float* __restrict__ cum_flow,
    const float* __restrict__ mask, const float* __restrict__ decay,
    float* __restrict__ out)
{
    const int w = threadIdx.x, h = blockIdx.x, t = blockIdx.y;
    const int pix = h * Wc + w;
    const float base_x = w * (2.0f / Wc) - 1.0f + 1.0f / Wc;
    const float base_y = h * (2.0f / Hc) - 1.0f + 1.0f / Hc;
    const float fxt = cum_flow[(t * 2 + 0) * HWc + pix];
    const float fyt = cum_flow[(t * 2 + 1) * HWc + pix];
    float acc[Cc];
#pragma unroll
    for (int c = 0; c < Cc; ++c) acc[c] = 0.0f;
    for (int k = 0; k <= t; ++k) {
        const float wkt = mask[t * Lc + k] * __expf(-DECAYc * decay[t * Lc + k]);
        const float fxk = cum_flow[(k * 2 + 0) * HWc + pix];
        const float fyk = cum_flow[(k * 2 + 1) * HWc + pix];
        float gx = base_x + (fxt - fxk);
        const float gy = base_y + (fyt - fyk);
        float m = gx + 1.0f;
        m -= 2.0f * floorf(m * 0.5f);
        gx = m - 1.0f;
        const float ix = (gx + 1.0f) * (Wc * 0.5f) - 0.5f;
        const float iy = (gy + 1.0f) * (Hc * 0.5f) - 0.5f;
        const float x0f = floorf(ix), y0f = floorf(iy);
        const float wx = ix - x0f, wy = iy - y0f;
        const int x0 = (int)x0f, y0 = (int)y0f;
        const int x0r = x0 & (Wc - 1), x1r = (x0 + 1) & (Wc - 1);
        const int y0c = min(max(y0, 0), Hc - 1), y1c = min(max(y0 + 1, 0), Hc - 1);
        const float a00 = wkt * (1.0f - wx) * (1.0f - wy);
        const float a01 = wkt * (1.0f - wx) * wy;
        const float a10 = wkt * wx * (1.0f - wy);
        const float a11 = wkt * wx * wy;
        const int o00 = y0c * Wc + x0r, o01 = y1c * Wc + x0r;
        const int o10 = y0c * Wc + x1r, o11 = y1c * Wc + x1r;
        const float* __restrict__ ik = img + (size_t)k * Cc * HWc;
#pragma unroll
        for (int c = 0; c < Cc; ++c) {
            const float* __restrict__ p = ik + c * HWc;
            acc[c] += p[o00] * a00 + p[o01] * a01 + p[o10] * a10 + p[o11] * a11;
        }
    }
    float* __restrict__ op = out + (size_t)t * Cc * HWc + pix;
#pragma unroll
    for (int c = 0; c < Cc; ++c) op[c * HWc] = acc[c];
}

extern "C" void kernel_launch(void* const* d_in, const int* in_sizes, int n_in,
                              void* d_out, int out_size, void* d_ws, size_t ws_size,
                              hipStream_t stream) {
    const float* img      = (const float*)d_in[0];
    const float* cum_flow = (const float*)d_in[1];
    const float* mask     = (const float*)d_in[2];
    const float* decay    = (const float*)d_in[3];
    float* out = (float*)d_out;

    const size_t needed = (size_t)Lc * HWc * Cc * sizeof(float);  // 32 MB
    if (ws_size >= needed) {
        float* imgT = (float*)d_ws;
        transpose_chlast<<<dim3(64 * Lc), 256, 0, stream>>>(img, imgT);
        gridsample_tquarter<<<dim3(2048), 256, 0, stream>>>(imgT, cum_flow, mask, decay, out);
    } else {
        dim3 grid(Hc, Lc, 1);
        gridsample_warp_acc<<<grid, Wc, 0, stream>>>(img, cum_flow, mask, decay, out);
    }
}